// Round 1
// baseline (877.532 us; speedup 1.0000x reference)
//
#include <hip/hip_runtime.h>
#include <hip/hip_bf16.h>

#define B_    16
#define NPTS_ 20000
#define H_    128
#define O_    4
#define L_    6
#define PDIM_ 8
#define K_    3

#define TPTS 64                      // points per tile
#define LPAD 133                     // LDS row stride (conflict-free: 8*133%32=8)
#define TILES_PER_B ((NPTS_ + TPTS - 1) / TPTS)   // 313

// ---------- activation helpers ----------
__device__ __forceinline__ float rowdy_act(float z, float a0, float a1, float a2) {
    // tanh(z) + a0*sin(z) + a1*sin(2z) + a2*sin(3z)
    float e  = __expf(2.f * z);                    // overflow -> inf -> th=1; underflow -> th=-1
    float th = 1.f - 2.f * __builtin_amdgcn_rcpf(e + 1.f);
    float s1 = __sinf(z);
    float c1 = __cosf(z);
    float s2 = 2.f * s1 * c1;
    float s3 = s1 * (3.f - 4.f * s1 * s1);
    return th + a0 * s1 + a1 * s2 + a2 * s3;
}

// ---------- branch tower + final-layer folding (tiny: 16 blocks x 128 thr) ----------
__global__ void branch_kernel(
    const float* __restrict__ params,
    const float* __restrict__ bW0, const float* __restrict__ bWr,
    const float* __restrict__ bb,  const float* __restrict__ bWout,
    const float* __restrict__ bbout,
    const float* __restrict__ fW,  const float* __restrict__ fb,
    float* __restrict__ S,         // [L][B][H] cumulative hidden sums
    float* __restrict__ M,         // [B][H][O]  fW @ ZL^T
    float* __restrict__ c0)        // [B][O]     fb . ZL
{
    const int b = blockIdx.x;
    const int j = threadIdx.x;     // 0..127
    __shared__ float h[H_];
    __shared__ float zl[O_][H_];

    // layer 0: params(8) -> H
    float z = bb[j];
    #pragma unroll
    for (int k = 0; k < PDIM_; ++k)
        z = fmaf(params[b * PDIM_ + k], bW0[k * H_ + j], z);
    float hv = tanhf(z);
    float srun = hv;
    h[j] = hv;
    S[(0 * B_ + b) * H_ + j] = srun;

    for (int i = 1; i < L_; ++i) {
        __syncthreads();           // h written
        const float* W = bWr + (size_t)(i - 1) * H_ * H_;
        float zz = bb[i * H_ + j];
        for (int k = 0; k < H_; ++k)
            zz = fmaf(h[k], W[k * H_ + j], zz);
        __syncthreads();           // done reading h
        hv = tanhf(zz);
        h[j] = hv;
        srun += hv;
        S[(i * B_ + b) * H_ + j] = srun;
    }
    __syncthreads();

    // branch_out -> ZL[o][j]  (Wout: (H, H*O) row-major)
    #pragma unroll
    for (int o = 0; o < O_; ++o) {
        float acc = bbout[o * H_ + j];
        for (int k = 0; k < H_; ++k)
            acc = fmaf(h[k], bWout[(size_t)k * (H_ * O_) + o * H_ + j], acc);
        zl[o][j] = acc;
    }
    __syncthreads();

    // M[b][j][o] = sum_h fW[j][h] * ZL[o][h]
    float m[O_] = {0.f, 0.f, 0.f, 0.f};
    for (int hh = 0; hh < H_; ++hh) {
        float w = fW[j * H_ + hh];
        #pragma unroll
        for (int o = 0; o < O_; ++o)
            m[o] = fmaf(w, zl[o][hh], m[o]);
    }
    #pragma unroll
    for (int o = 0; o < O_; ++o)
        M[((size_t)b * H_ + j) * O_ + o] = m[o];

    if (j < O_) {
        float acc = 0.f;
        for (int hh = 0; hh < H_; ++hh)
            acc = fmaf(fb[hh], zl[j][hh], acc);
        c0[b * O_ + j] = acc;
    }
}

// ---------- trunk: 64-pt tiles, 128 threads, 8pt x 8j register blocking ----------
__global__ __launch_bounds__(128) void trunk_kernel(
    const float* __restrict__ coords, const float* __restrict__ sdf,
    const float* __restrict__ tW0,    const float* __restrict__ tWr,
    const float* __restrict__ tb,     const float* __restrict__ ra,
    const float* __restrict__ S,      const float* __restrict__ M,
    const float* __restrict__ c0,     float* __restrict__ out)
{
    __shared__ float xs[TPTS][LPAD];

    const int blk  = blockIdx.x;
    const int b    = blk / TILES_PER_B;
    const int tile = blk % TILES_PER_B;
    const int p0   = tile * TPTS;
    const int t    = threadIdx.x;
    const int jg   = t & 15;      // 16 j-groups of 8  -> 128 cols
    const int pg   = t >> 4;      // 8  p-groups of 8  -> 64 rows
    const int j0   = jg * 8;
    const int pb   = pg * 8;

    // ---- layer 0: (coords,sdf) -> H, rowdy, * S0 ----
    {
        float w[4][8];
        #pragma unroll
        for (int c = 0; c < 4; ++c) {
            float4 lo = *(const float4*)(tW0 + c * H_ + j0);
            float4 hi = *(const float4*)(tW0 + c * H_ + j0 + 4);
            w[c][0] = lo.x; w[c][1] = lo.y; w[c][2] = lo.z; w[c][3] = lo.w;
            w[c][4] = hi.x; w[c][5] = hi.y; w[c][6] = hi.z; w[c][7] = hi.w;
        }
        float bias[8], a0[8], a1[8], a2[8], Sv[8];
        #pragma unroll
        for (int jj = 0; jj < 8; ++jj) {
            bias[jj] = tb[0 * H_ + j0 + jj];
            a0[jj]   = ra[(0 * K_ + 0) * H_ + j0 + jj];
            a1[jj]   = ra[(0 * K_ + 1) * H_ + j0 + jj];
            a2[jj]   = ra[(0 * K_ + 2) * H_ + j0 + jj];
            Sv[jj]   = S [(0 * B_ + b) * H_ + j0 + jj];
        }
        #pragma unroll
        for (int pp = 0; pp < 8; ++pp) {
            int p  = p0 + pb + pp;
            int pc = p < NPTS_ ? p : NPTS_ - 1;
            size_t gp = (size_t)b * NPTS_ + pc;
            float in0 = coords[gp * 3 + 0];
            float in1 = coords[gp * 3 + 1];
            float in2 = coords[gp * 3 + 2];
            float in3 = sdf[gp];
            #pragma unroll
            for (int jj = 0; jj < 8; ++jj) {
                float z = bias[jj];
                z = fmaf(in0, w[0][jj], z);
                z = fmaf(in1, w[1][jj], z);
                z = fmaf(in2, w[2][jj], z);
                z = fmaf(in3, w[3][jj], z);
                xs[pb + pp][j0 + jj] = rowdy_act(z, a0[jj], a1[jj], a2[jj]) * Sv[jj];
            }
        }
    }
    __syncthreads();

    // ---- layers 1..5: x = rowdy(x@W + b) * S_i ----
    for (int i = 1; i < L_; ++i) {
        const float* W = tWr + (size_t)(i - 1) * H_ * H_;
        float bias[8];
        #pragma unroll
        for (int jj = 0; jj < 8; ++jj) bias[jj] = tb[i * H_ + j0 + jj];

        float acc[8][8];
        #pragma unroll
        for (int pp = 0; pp < 8; ++pp)
            #pragma unroll
            for (int jj = 0; jj < 8; ++jj) acc[pp][jj] = bias[jj];

        #pragma unroll 2
        for (int k = 0; k < H_; ++k) {
            float xv[8];
            #pragma unroll
            for (int pp = 0; pp < 8; ++pp) xv[pp] = xs[pb + pp][k];
            float4 wlo = *(const float4*)(W + (size_t)k * H_ + j0);
            float4 whi = *(const float4*)(W + (size_t)k * H_ + j0 + 4);
            float wv[8] = {wlo.x, wlo.y, wlo.z, wlo.w, whi.x, whi.y, whi.z, whi.w};
            #pragma unroll
            for (int pp = 0; pp < 8; ++pp)
                #pragma unroll
                for (int jj = 0; jj < 8; ++jj)
                    acc[pp][jj] = fmaf(xv[pp], wv[jj], acc[pp][jj]);
        }
        __syncthreads();   // everyone done reading xs

        float a0[8], a1[8], a2[8], Sv[8];
        #pragma unroll
        for (int jj = 0; jj < 8; ++jj) {
            a0[jj] = ra[(i * K_ + 0) * H_ + j0 + jj];
            a1[jj] = ra[(i * K_ + 1) * H_ + j0 + jj];
            a2[jj] = ra[(i * K_ + 2) * H_ + j0 + jj];
            Sv[jj] = S [(i * B_ + b) * H_ + j0 + jj];
        }
        #pragma unroll
        for (int pp = 0; pp < 8; ++pp)
            #pragma unroll
            for (int jj = 0; jj < 8; ++jj)
                xs[pb + pp][j0 + jj] =
                    rowdy_act(acc[pp][jj], a0[jj], a1[jj], a2[jj]) * Sv[jj];
        __syncthreads();   // writes visible
    }

    // ---- fused final layer + O-contraction: out[p][o] = c0 + sum_k x[k]*M[k][o] ----
    {
        const int p  = t >> 1;            // 0..63
        const int oo = (t & 1) * 2;       // 0 or 2
        float acc0 = c0[b * O_ + oo];
        float acc1 = c0[b * O_ + oo + 1];
        const float* Mb = M + (size_t)b * H_ * O_;
        #pragma unroll 4
        for (int k = 0; k < H_; ++k) {
            float xv = xs[p][k];
            float2 mv = *(const float2*)(Mb + k * O_ + oo);
            acc0 = fmaf(xv, mv.x, acc0);
            acc1 = fmaf(xv, mv.y, acc1);
        }
        int gp = p0 + p;
        if (gp < NPTS_) {
            float2 o2 = make_float2(acc0, acc1);
            *(float2*)(out + ((size_t)b * NPTS_ + gp) * O_ + oo) = o2;
        }
    }
}

extern "C" void kernel_launch(void* const* d_in, const int* in_sizes, int n_in,
                              void* d_out, int out_size, void* d_ws, size_t ws_size,
                              hipStream_t stream) {
    const float* coords  = (const float*)d_in[0];
    const float* sdf     = (const float*)d_in[1];
    const float* params  = (const float*)d_in[2];
    const float* bW0     = (const float*)d_in[3];
    const float* bWr     = (const float*)d_in[4];
    const float* bb      = (const float*)d_in[5];
    const float* bWout   = (const float*)d_in[6];
    const float* bbout   = (const float*)d_in[7];
    const float* tW0     = (const float*)d_in[8];
    const float* tWr     = (const float*)d_in[9];
    const float* tb      = (const float*)d_in[10];
    const float* ra      = (const float*)d_in[11];
    const float* fW      = (const float*)d_in[12];
    const float* fb      = (const float*)d_in[13];
    float* out = (float*)d_out;

    float* S  = (float*)d_ws;                       // 6*16*128 = 12288
    float* M  = S + (size_t)L_ * B_ * H_;           // 16*128*4 =  8192
    float* c0 = M + (size_t)B_ * H_ * O_;           // 16*4     =    64

    branch_kernel<<<dim3(B_), dim3(H_), 0, stream>>>(
        params, bW0, bWr, bb, bWout, bbout, fW, fb, S, M, c0);

    trunk_kernel<<<dim3(B_ * TILES_PER_B), dim3(128), 0, stream>>>(
        coords, sdf, tW0, tWr, tb, ra, S, M, c0, out);
}

// Round 2
// 522.445 us; speedup vs baseline: 1.6797x; 1.6797x over previous
//
#include <hip/hip_runtime.h>
#include <hip/hip_bf16.h>
#include <stdint.h>

#define B_    16
#define NPTS_ 20000
#define H_    128
#define O_    4
#define L_    6
#define PDIM_ 8
#define K_    3

#define TPTS 64
#define KSTR 136                                   // ushort row stride (+8 pad)
#define TILES_PER_B ((NPTS_ + TPTS - 1) / TPTS)    // 313

typedef __attribute__((ext_vector_type(8))) short short8;
typedef __attribute__((ext_vector_type(4))) float f32x4;
typedef __attribute__((ext_vector_type(4))) unsigned short us4;

// ---------- bf16 helpers ----------
__device__ __forceinline__ uint16_t f2bf(float x) {
    uint32_t u = __float_as_uint(x);
    uint32_t r = u + 0x7FFFu + ((u >> 16) & 1u);
    return (uint16_t)(r >> 16);
}
__device__ __forceinline__ float bf2f(uint16_t h) {
    return __uint_as_float(((uint32_t)h) << 16);
}

// ---------- activation ----------
__device__ __forceinline__ float rowdy_act(float z, float a0, float a1, float a2) {
    float e  = __expf(2.f * z);
    float th = 1.f - 2.f * __builtin_amdgcn_rcpf(e + 1.f);
    float s1 = __sinf(z);
    float c1 = __cosf(z);
    float s2 = 2.f * s1 * c1;
    float s3 = s1 * (3.f - 4.f * s1 * s1);
    return th + a0 * s1 + a1 * s2 + a2 * s3;
}
__device__ __forceinline__ void act_split(float z, float a0, float a1, float a2,
                                          float s, uint16_t& h, uint16_t& l) {
    float x = rowdy_act(z, a0, a1, a2) * s;
    h = f2bf(x);
    l = f2bf(x - bf2f(h));
}

// ---------- weight prep: transpose + bf16 split ----------
__global__ void prep_w(const float* __restrict__ tWr,
                       uint16_t* __restrict__ WtHi, uint16_t* __restrict__ WtLo) {
    const int bid = blockIdx.x;        // 0..639
    const int l   = bid >> 7;          // 0..4
    const int j   = bid & 127;
    const int k   = threadIdx.x;       // 0..127
    float w = tWr[((size_t)l * H_ + k) * H_ + j];
    uint16_t h = f2bf(w);
    uint16_t lo = f2bf(w - bf2f(h));
    WtHi[((size_t)l * H_ + j) * H_ + k] = h;
    WtLo[((size_t)l * H_ + j) * H_ + k] = lo;
}

// ---------- branch tower (unchanged, tiny) ----------
__global__ void branch_kernel(
    const float* __restrict__ params,
    const float* __restrict__ bW0, const float* __restrict__ bWr,
    const float* __restrict__ bb,  const float* __restrict__ bWout,
    const float* __restrict__ bbout,
    const float* __restrict__ fW,  const float* __restrict__ fb,
    float* __restrict__ S, float* __restrict__ M, float* __restrict__ c0)
{
    const int b = blockIdx.x;
    const int j = threadIdx.x;
    __shared__ float h[H_];
    __shared__ float zl[O_][H_];

    float z = bb[j];
    #pragma unroll
    for (int k = 0; k < PDIM_; ++k)
        z = fmaf(params[b * PDIM_ + k], bW0[k * H_ + j], z);
    float hv = tanhf(z);
    float srun = hv;
    h[j] = hv;
    S[(0 * B_ + b) * H_ + j] = srun;

    for (int i = 1; i < L_; ++i) {
        __syncthreads();
        const float* W = bWr + (size_t)(i - 1) * H_ * H_;
        float zz = bb[i * H_ + j];
        for (int k = 0; k < H_; ++k)
            zz = fmaf(h[k], W[k * H_ + j], zz);
        __syncthreads();
        hv = tanhf(zz);
        h[j] = hv;
        srun += hv;
        S[(i * B_ + b) * H_ + j] = srun;
    }
    __syncthreads();

    #pragma unroll
    for (int o = 0; o < O_; ++o) {
        float acc = bbout[o * H_ + j];
        for (int k = 0; k < H_; ++k)
            acc = fmaf(h[k], bWout[(size_t)k * (H_ * O_) + o * H_ + j], acc);
        zl[o][j] = acc;
    }
    __syncthreads();

    float m[O_] = {0.f, 0.f, 0.f, 0.f};
    for (int hh = 0; hh < H_; ++hh) {
        float w = fW[j * H_ + hh];
        #pragma unroll
        for (int o = 0; o < O_; ++o)
            m[o] = fmaf(w, zl[o][hh], m[o]);
    }
    #pragma unroll
    for (int o = 0; o < O_; ++o)
        M[((size_t)b * H_ + j) * O_ + o] = m[o];

    if (j < O_) {
        float acc = 0.f;
        for (int hh = 0; hh < H_; ++hh)
            acc = fmaf(fb[hh], zl[j][hh], acc);
        c0[b * O_ + j] = acc;
    }
}

// ---------- trunk: split-bf16 MFMA ----------
__global__ __launch_bounds__(256, 4) void trunk_mfma(
    const float* __restrict__ coords, const float* __restrict__ sdf,
    const float* __restrict__ tW0,    const float* __restrict__ tb,
    const float* __restrict__ ra,     const float* __restrict__ S,
    const float* __restrict__ M,      const float* __restrict__ c0,
    const uint16_t* __restrict__ WtHi, const uint16_t* __restrict__ WtLo,
    float* __restrict__ out)
{
    __shared__ __align__(16) uint16_t Xhi[TPTS][KSTR];
    __shared__ __align__(16) uint16_t Xlo[TPTS][KSTR];

    const int blk  = blockIdx.x;
    const int b    = blk / TILES_PER_B;
    const int tile = blk % TILES_PER_B;
    const int p0   = tile * TPTS;
    const int t    = threadIdx.x;

    // ---- layer 0 (fp32 VALU, 4->128) ----
    {
        const int p = t >> 2;
        const int q = t & 3;
        int pg = p0 + p;
        int pc = pg < NPTS_ ? pg : NPTS_ - 1;
        size_t gp = (size_t)b * NPTS_ + pc;
        float in0 = coords[gp * 3 + 0], in1 = coords[gp * 3 + 1];
        float in2 = coords[gp * 3 + 2], in3 = sdf[gp];
        #pragma unroll
        for (int jj = 0; jj < 32; jj += 4) {
            const int j = q * 32 + jj;
            float4 w0 = *(const float4*)(tW0 + 0 * H_ + j);
            float4 w1 = *(const float4*)(tW0 + 1 * H_ + j);
            float4 w2 = *(const float4*)(tW0 + 2 * H_ + j);
            float4 w3 = *(const float4*)(tW0 + 3 * H_ + j);
            float4 bv = *(const float4*)(tb + j);
            float4 A0 = *(const float4*)(ra + 0 * H_ + j);
            float4 A1 = *(const float4*)(ra + 1 * H_ + j);
            float4 A2 = *(const float4*)(ra + 2 * H_ + j);
            float4 Sv = *(const float4*)(S + b * H_ + j);
            float z0 = fmaf(in3, w3.x, fmaf(in2, w2.x, fmaf(in1, w1.x, fmaf(in0, w0.x, bv.x))));
            float z1 = fmaf(in3, w3.y, fmaf(in2, w2.y, fmaf(in1, w1.y, fmaf(in0, w0.y, bv.y))));
            float z2 = fmaf(in3, w3.z, fmaf(in2, w2.z, fmaf(in1, w1.z, fmaf(in0, w0.z, bv.z))));
            float z3 = fmaf(in3, w3.w, fmaf(in2, w2.w, fmaf(in1, w1.w, fmaf(in0, w0.w, bv.w))));
            us4 h4, l4;
            uint16_t hh, ll;
            act_split(z0, A0.x, A1.x, A2.x, Sv.x, hh, ll); h4[0] = hh; l4[0] = ll;
            act_split(z1, A0.y, A1.y, A2.y, Sv.y, hh, ll); h4[1] = hh; l4[1] = ll;
            act_split(z2, A0.z, A1.z, A2.z, Sv.z, hh, ll); h4[2] = hh; l4[2] = ll;
            act_split(z3, A0.w, A1.w, A2.w, Sv.w, hh, ll); h4[3] = hh; l4[3] = ll;
            *(us4*)(&Xhi[p][j]) = h4;
            *(us4*)(&Xlo[p][j]) = l4;
        }
    }
    __syncthreads();

    // ---- layers 1..5 via MFMA (D[j][p], split-bf16 3-term) ----
    const int ln    = t & 63;
    const int wv    = t >> 6;          // wave 0..3 -> j-slice of 32
    const int l15   = ln & 15;
    const int l4    = ln >> 4;
    const int jbase = wv * 32;

    for (int layer = 1; layer < L_; ++layer) {
        f32x4 acc[2][4];
        #pragma unroll
        for (int jf = 0; jf < 2; ++jf) {
            const int j = jbase + jf * 16 + l4 * 4;
            float4 bv = *(const float4*)(tb + layer * H_ + j);
            #pragma unroll
            for (int pf = 0; pf < 4; ++pf)
                acc[jf][pf] = (f32x4){bv.x, bv.y, bv.z, bv.w};
        }
        const uint16_t* WH = WtHi + (size_t)(layer - 1) * H_ * H_;
        const uint16_t* WL = WtLo + (size_t)(layer - 1) * H_ * H_;
        #pragma unroll
        for (int ks = 0; ks < 4; ++ks) {
            const int kpos = ks * 32 + l4 * 8;
            short8 aH[2], aL[2];
            #pragma unroll
            for (int jf = 0; jf < 2; ++jf) {
                const int j = jbase + jf * 16 + l15;
                aH[jf] = *(const short8*)(WH + (size_t)j * H_ + kpos);
                aL[jf] = *(const short8*)(WL + (size_t)j * H_ + kpos);
            }
            #pragma unroll
            for (int pf = 0; pf < 4; ++pf) {
                const int prow = pf * 16 + l15;
                short8 bH = *(const short8*)(&Xhi[prow][kpos]);
                short8 bL = *(const short8*)(&Xlo[prow][kpos]);
                #pragma unroll
                for (int jf = 0; jf < 2; ++jf) {
                    acc[jf][pf] = __builtin_amdgcn_mfma_f32_16x16x32_bf16(aH[jf], bH, acc[jf][pf], 0, 0, 0);
                    acc[jf][pf] = __builtin_amdgcn_mfma_f32_16x16x32_bf16(aH[jf], bL, acc[jf][pf], 0, 0, 0);
                    acc[jf][pf] = __builtin_amdgcn_mfma_f32_16x16x32_bf16(aL[jf], bH, acc[jf][pf], 0, 0, 0);
                }
            }
        }
        __syncthreads();   // all reads of X done

        #pragma unroll
        for (int jf = 0; jf < 2; ++jf) {
            const int j = jbase + jf * 16 + l4 * 4;
            float4 A0 = *(const float4*)(ra + (layer * K_ + 0) * H_ + j);
            float4 A1 = *(const float4*)(ra + (layer * K_ + 1) * H_ + j);
            float4 A2 = *(const float4*)(ra + (layer * K_ + 2) * H_ + j);
            float4 Sv = *(const float4*)(S + (layer * B_ + b) * H_ + j);
            #pragma unroll
            for (int pf = 0; pf < 4; ++pf) {
                const int prow = pf * 16 + l15;
                us4 h4, l4v;
                uint16_t hh, ll;
                act_split(acc[jf][pf][0], A0.x, A1.x, A2.x, Sv.x, hh, ll); h4[0] = hh; l4v[0] = ll;
                act_split(acc[jf][pf][1], A0.y, A1.y, A2.y, Sv.y, hh, ll); h4[1] = hh; l4v[1] = ll;
                act_split(acc[jf][pf][2], A0.z, A1.z, A2.z, Sv.z, hh, ll); h4[2] = hh; l4v[2] = ll;
                act_split(acc[jf][pf][3], A0.w, A1.w, A2.w, Sv.w, hh, ll); h4[3] = hh; l4v[3] = ll;
                *(us4*)(&Xhi[prow][j]) = h4;
                *(us4*)(&Xlo[prow][j]) = l4v;
            }
        }
        __syncthreads();   // writes visible
    }

    // ---- fused final layer + O-contraction ----
    {
        const int p = t >> 2;
        const int o = t & 3;
        float acc = c0[b * O_ + o];
        const float* Mb = M + (size_t)b * H_ * O_;
        #pragma unroll 4
        for (int k = 0; k < H_; k += 8) {
            short8 h8 = *(const short8*)(&Xhi[p][k]);
            short8 l8 = *(const short8*)(&Xlo[p][k]);
            #pragma unroll
            for (int e = 0; e < 8; ++e) {
                float xv = bf2f((uint16_t)h8[e]) + bf2f((uint16_t)l8[e]);
                acc = fmaf(xv, Mb[(k + e) * O_ + o], acc);
            }
        }
        int gp = p0 + p;
        if (gp < NPTS_)
            out[((size_t)b * NPTS_ + gp) * O_ + o] = acc;
    }
}

extern "C" void kernel_launch(void* const* d_in, const int* in_sizes, int n_in,
                              void* d_out, int out_size, void* d_ws, size_t ws_size,
                              hipStream_t stream) {
    const float* coords  = (const float*)d_in[0];
    const float* sdf     = (const float*)d_in[1];
    const float* params  = (const float*)d_in[2];
    const float* bW0     = (const float*)d_in[3];
    const float* bWr     = (const float*)d_in[4];
    const float* bb      = (const float*)d_in[5];
    const float* bWout   = (const float*)d_in[6];
    const float* bbout   = (const float*)d_in[7];
    const float* tW0     = (const float*)d_in[8];
    const float* tWr     = (const float*)d_in[9];
    const float* tb      = (const float*)d_in[10];
    const float* ra      = (const float*)d_in[11];
    const float* fW      = (const float*)d_in[12];
    const float* fb      = (const float*)d_in[13];
    float* out = (float*)d_out;

    float* S  = (float*)d_ws;                          // 6*16*128 floats
    float* M  = S + (size_t)L_ * B_ * H_;              // 16*128*4
    float* c0 = M + (size_t)B_ * H_ * O_;              // 64
    uint16_t* WtHi = (uint16_t*)(c0 + B_ * O_);        // 5*128*128 ushort
    uint16_t* WtLo = WtHi + (size_t)(L_ - 1) * H_ * H_;

    prep_w<<<dim3((L_ - 1) * H_), dim3(H_), 0, stream>>>(tWr, WtHi, WtLo);
    branch_kernel<<<dim3(B_), dim3(H_), 0, stream>>>(
        params, bW0, bWr, bb, bWout, bbout, fW, fb, S, M, c0);
    trunk_mfma<<<dim3(B_ * TILES_PER_B), dim3(256), 0, stream>>>(
        coords, sdf, tW0, tb, ra, S, M, c0, WtHi, WtLo, out);
}